// Round 2
// baseline (687.567 us; speedup 1.0000x reference)
//
#include <hip/hip_runtime.h>
#include <hip/hip_bf16.h>
#include <stdint.h>

#define C_   192
#define H_   256
#define W_   256
#define HW_  65536
#define CHW  12582912
#define NH_  6
#define HID_ 384

typedef __attribute__((ext_vector_type(8))) __bf16 bf16x8;
typedef __attribute__((ext_vector_type(8))) uint16_t u16x8;
typedef __attribute__((ext_vector_type(4))) float  fx4;

__device__ __forceinline__ uint16_t f2bf(float f) {
  uint32_t u = __builtin_bit_cast(uint32_t, f);
  u += 0x7fffu + ((u >> 16) & 1u);
  return (uint16_t)(u >> 16);
}
__device__ __forceinline__ float bf2f(uint16_t h) {
  uint32_t u = ((uint32_t)h) << 16;
  return __builtin_bit_cast(float, u);
}
__device__ __forceinline__ uint32_t pk2(float a, float b) {
  return (uint32_t)f2bf(a) | ((uint32_t)f2bf(b) << 16);
}
__device__ __forceinline__ bf16x8 ld8(const uint16_t* p) {
  uint4 v = *reinterpret_cast<const uint4*>(p);
  return __builtin_bit_cast(bf16x8, v);
}
__device__ __forceinline__ fx4 mfma16(bf16x8 a, bf16x8 b, fx4 c) {
  return __builtin_amdgcn_mfma_f32_16x16x32_bf16(a, b, c, 0, 0, 0);
}
// tanh-form GELU: 0.5v(1+tanh(0.79788456(v+0.044715 v^3)))
// exp2-based; max |err| vs erf-GELU ~3e-4 (<< bf16 rounding of hidden acts).
__device__ __forceinline__ float gelu_f(float v) {
  float c2 = v * v;
  float u = __builtin_fmaf(c2, 0.044715f, 1.0f) * v;   // v + 0.044715 v^3
  float e = exp2f(u * 2.3022084f);                     // exp(2*0.79788456*u)
  float th = 1.0f - 2.0f * __builtin_amdgcn_rcpf(1.0f + e);
  float hv = 0.5f * v;
  return __builtin_fmaf(hv, th, hv);
}

// ---------------- K0: weight prep (transpose to bf16 B-fragment layout) ----------------
// fc1 weights get LN2's n2w folded in; b1f = fc1_b + n2b . fc1_w (exact LN-affine fold).
__global__ __launch_bounds__(256) void prep_kernel(
    const float* __restrict__ qkv_w, const float* __restrict__ proj_w,
    const float* __restrict__ fc1_w, const float* __restrict__ fc2_w,
    const float* __restrict__ rpb, const float* __restrict__ n2w,
    const float* __restrict__ n2b, const float* __restrict__ fc1_b,
    uint16_t* __restrict__ qkv_wt, uint16_t* __restrict__ proj_wt,
    uint16_t* __restrict__ fc1_wt, uint16_t* __restrict__ fc2_wt,
    float* __restrict__ rpbb, float* __restrict__ b1f) {
  int tid = blockIdx.x * 256 + threadIdx.x;
  if (tid < 576 * 192) {                       // qkv_wt[f][k] = qkv_w[k][f]
    int f = tid / 192, k = tid % 192;
    qkv_wt[tid] = f2bf(qkv_w[k * 576 + f]);
  }
  int t1 = tid - 576 * 192;
  if (t1 >= 0 && t1 < 192 * 192) {             // proj_wt[f][k]
    int f = t1 / 192, k = t1 % 192;
    proj_wt[t1] = f2bf(proj_w[k * 192 + f]);
  }
  int t2 = t1 - 192 * 192;
  if (t2 >= 0 && t2 < 384 * 192) {             // fc1_wt[f][k] = fc1_w[k][f]*n2w[k]
    int f = t2 / 192, k = t2 % 192;
    fc1_wt[t2] = f2bf(fc1_w[k * 384 + f] * n2w[k]);
  }
  int t3 = t2 - 384 * 192;
  if (t3 >= 0 && t3 < 192 * 384) {             // fc2_wt[o][k]
    int f = t3 / 384, k = t3 % 384;
    fc2_wt[t3] = f2bf(fc2_w[k * 192 + f]);
  }
  int t4 = t3 - 192 * 384;
  if (t4 >= 0 && t4 < 6 * 64 * 64) {           // rpbb[h][n][m]
    int h = t4 / 4096, nm = t4 % 4096, n = nm / 64, m = nm % 64;
    int yn = n >> 3, xn = n & 7, ym = m >> 3, xm = m & 7;
    int idx = (yn - ym + 7) * 15 + (xn - xm + 7);
    rpbb[t4] = rpb[idx * NH_ + h];
  }
  int t5 = t4 - 6 * 64 * 64;
  if (t5 >= 0 && t5 < 384) {                   // folded fc1 bias
    float acc = fc1_b[t5];
    for (int c = 0; c < 192; c++) acc = __builtin_fmaf(n2b[c], fc1_w[c * 384 + t5], acc);
    b1f[t5] = acc;
  }
}

// ---------------- K1a: LN1 stats (mu, rsig per pixel) ----------------
__global__ __launch_bounds__(256) void ln1_stats(const float* __restrict__ x,
                                                 float* __restrict__ mu,
                                                 float* __restrict__ rsig) {
  int t = blockIdx.x * 256 + threadIdx.x;   // (b,hw)
  int b = t >> 16, hw = t & 65535;
  const float* xp = x + (size_t)b * CHW + hw;
  float s = 0.f, sq = 0.f;
#pragma unroll 8
  for (int c = 0; c < C_; c++) {
    float v = xp[(size_t)c * HW_];
    s += v; sq += v * v;
  }
  float m = s * (1.0f / C_);
  float var = sq * (1.0f / C_) - m * m;
  mu[t] = m;
  rsig[t] = rsqrtf(var + 1e-6f);
}

// ---------------- K1b: apply LN1 + roll-reinterpret shuffle + transpose -> token-major bf16 --
__global__ __launch_bounds__(256) void ln1_apply_kernel(
    const float* __restrict__ x, const float* __restrict__ mu, const float* __restrict__ rsig,
    const float* __restrict__ n1w, const float* __restrict__ n1b,
    uint16_t* __restrict__ y_tok) {
  __shared__ __attribute__((aligned(16))) uint16_t tile[192 * 66];
  int wg = blockIdx.x;
  int b = wg >> 10, hw0 = (wg & 1023) << 6;
  int t = threadIdx.x;
  const float* xb = x + (size_t)b * CHW;
  const float* mub = mu + b * HW_;
  const float* rsb = rsig + b * HW_;
#pragma unroll 4
  for (int it = 0; it < 48; it++) {
    int id = it * 256 + t;
    int ca = id >> 6, pp = id & 63;
    int g = ca * 65536 + hw0 + pp;
    int h2 = g / 49152;
    int r = g - h2 * 49152;
    int w2 = r / 192;
    int c2 = r - w2 * 192;
    int f = ((h2 + 4) & 255) * 49152 + ((w2 + 4) & 255) * 192 + c2;
    int cnat = f >> 16;
    int hwn = f & 65535;
    float v = (xb[f] - mub[hwn]) * rsb[hwn] * n1w[cnat] + n1b[cnat];
    tile[ca * 66 + pp] = f2bf(v);
  }
  __syncthreads();
  uint16_t* yb = y_tok + ((size_t)(b * HW_ + hw0)) * C_;
#pragma unroll 4
  for (int it = 0; it < 48; it++) {
    int id = it * 256 + t;
    int pp = id / 192, ca = id - pp * 192;
    yb[id] = tile[ca * 66 + pp];
  }
}

// ---------------- K2: fused window attention + fused GAP partials ----------------
__global__ __launch_bounds__(256, 2) void attn_kernel(
    const uint16_t* __restrict__ y_tok, const uint16_t* __restrict__ qkv_wt,
    const float* __restrict__ qkv_b, const uint16_t* __restrict__ proj_wt,
    const float* __restrict__ proj_b, const float* __restrict__ rpbb,
    uint16_t* __restrict__ y_attn, float* __restrict__ part) {
  __shared__ __attribute__((aligned(16))) uint16_t Qs[64 * 200]; // Q, later O
  __shared__ __attribute__((aligned(16))) uint16_t Ks[64 * 200];
  __shared__ __attribute__((aligned(16))) uint16_t VT[32 * 72];
  __shared__ __attribute__((aligned(16))) uint16_t Ps[64 * 72];
  const int wg = blockIdx.x;
  const int b = wg >> 10, wid = wg & 1023;
  const int wh = wid >> 5, ww = wid & 31;
  const int t = threadIdx.x;
  const int w = t >> 6, l = t & 63;
  const int lane16 = l & 15, quad = l >> 4;
  const int trow = w * 16 + quad * 4;

  bf16x8 afr[4][6];
#pragma unroll
  for (int m = 0; m < 4; m++) {
    const int tok = m * 16 + lane16;
    const uint16_t* ap = y_tok +
        ((size_t)(b * HW_ + (wh * 8 + (tok >> 3)) * W_ + ww * 8 + (tok & 7))) * C_ + quad * 8;
#pragma unroll
    for (int k = 0; k < 6; k++) afr[m][k] = ld8(ap + k * 32);
  }

  const float scale = 0.17677669529663687f;
  uint32_t vpack[3][4][2];

#pragma unroll
  for (int j = 0; j < 3; j++) {
    const int nt = w + 4 * j;
    const uint16_t* bp = qkv_wt + (nt * 16 + lane16) * C_ + quad * 8;
    bf16x8 bfr[6];
#pragma unroll
    for (int k = 0; k < 6; k++) bfr[k] = ld8(bp + k * 32);
    fx4 acc[4];
#pragma unroll
    for (int m = 0; m < 4; m++) acc[m] = fx4{0.f, 0.f, 0.f, 0.f};
#pragma unroll
    for (int k = 0; k < 6; k++)
#pragma unroll
      for (int m = 0; m < 4; m++) acc[m] = mfma16(afr[m][k], bfr[k], acc[m]);
    const int f = nt * 16 + lane16;
    const float bias = qkv_b[f];
#pragma unroll
    for (int m = 0; m < 4; m++)
#pragma unroll
      for (int r = 0; r < 4; r++)
        Qs[(m * 16 + quad * 4 + r) * 200 + f] = f2bf((acc[m][r] + bias) * scale);
  }
#pragma unroll
  for (int j = 3; j < 6; j++) {
    const int nt = w + 4 * j;
    const uint16_t* bp = qkv_wt + (nt * 16 + lane16) * C_ + quad * 8;
    bf16x8 bfr[6];
#pragma unroll
    for (int k = 0; k < 6; k++) bfr[k] = ld8(bp + k * 32);
    fx4 acc[4];
#pragma unroll
    for (int m = 0; m < 4; m++) acc[m] = fx4{0.f, 0.f, 0.f, 0.f};
#pragma unroll
    for (int k = 0; k < 6; k++)
#pragma unroll
      for (int m = 0; m < 4; m++) acc[m] = mfma16(afr[m][k], bfr[k], acc[m]);
    const int f = nt * 16 + lane16;
    const float bias = qkv_b[f];
#pragma unroll
    for (int m = 0; m < 4; m++)
#pragma unroll
      for (int r = 0; r < 4; r++)
        Ks[(m * 16 + quad * 4 + r) * 200 + (f - 192)] = f2bf(acc[m][r] + bias);
  }
#pragma unroll
  for (int j = 6; j < 9; j++) {
    const int nt = w + 4 * j;
    const uint16_t* bp = qkv_wt + (nt * 16 + lane16) * C_ + quad * 8;
    bf16x8 bfr[6];
#pragma unroll
    for (int k = 0; k < 6; k++) bfr[k] = ld8(bp + k * 32);
    fx4 acc[4];
#pragma unroll
    for (int m = 0; m < 4; m++) acc[m] = fx4{0.f, 0.f, 0.f, 0.f};
#pragma unroll
    for (int k = 0; k < 6; k++)
#pragma unroll
      for (int m = 0; m < 4; m++) acc[m] = mfma16(afr[m][k], bfr[k], acc[m]);
    const float bias = qkv_b[nt * 16 + lane16];
    const int jv = j - 6;
#pragma unroll
    for (int m = 0; m < 4; m++) {
      vpack[jv][m][0] = pk2(acc[m][0] + bias, acc[m][1] + bias);
      vpack[jv][m][1] = pk2(acc[m][2] + bias, acc[m][3] + bias);
    }
  }

  const bool whe = (wh == 31), wwe = (ww == 31);

  for (int h = 0; h < 6; h++) {
    __syncthreads();
    {
      const int vt0 = 2 * h, vt1 = 2 * h + 1;
      if (w == (vt0 & 3)) {
        const int jv = vt0 >> 2;
#pragma unroll
        for (int m = 0; m < 4; m++) {
          uint2 vv; vv.x = vpack[jv][m][0]; vv.y = vpack[jv][m][1];
          *reinterpret_cast<uint2*>(&VT[lane16 * 72 + m * 16 + quad * 4]) = vv;
        }
      }
      if (w == (vt1 & 3)) {
        const int jv = vt1 >> 2;
#pragma unroll
        for (int m = 0; m < 4; m++) {
          uint2 vv; vv.x = vpack[jv][m][0]; vv.y = vpack[jv][m][1];
          *reinterpret_cast<uint2*>(&VT[(16 + lane16) * 72 + m * 16 + quad * 4]) = vv;
        }
      }
    }
    __syncthreads();

    const bf16x8 qa = ld8(&Qs[(w * 16 + lane16) * 200 + h * 32 + quad * 8]);
    fx4 sacc[4];
#pragma unroll
    for (int nt = 0; nt < 4; nt++) {
      const bf16x8 kb = ld8(&Ks[(nt * 16 + lane16) * 200 + h * 32 + quad * 8]);
      fx4 z = {0.f, 0.f, 0.f, 0.f};
      sacc[nt] = mfma16(qa, kb, z);
    }
    const float* rb = rpbb + h * 4096;
#pragma unroll
    for (int nt = 0; nt < 4; nt++) {
      const int ct = nt * 16 + lane16;
      const bool rbc = whe && ((ct >> 3) >= 4);
      const bool cbc = wwe && ((ct & 7) >= 4);
#pragma unroll
      for (int r = 0; r < 4; r++) {
        const int rt = trow + r;
        const bool rbr = whe && ((rt >> 3) >= 4);
        const bool cbr = wwe && ((rt & 7) >= 4);
        float v = sacc[nt][r] + rb[rt * 64 + ct];
        if (rbr != rbc || cbr != cbc) v -= 100.f;
        sacc[nt][r] = v;
      }
    }
    float sm[4];
#pragma unroll
    for (int r = 0; r < 4; r++) {
      float m = fmaxf(fmaxf(sacc[0][r], sacc[1][r]), fmaxf(sacc[2][r], sacc[3][r]));
      m = fmaxf(m, __shfl_xor(m, 1));
      m = fmaxf(m, __shfl_xor(m, 2));
      m = fmaxf(m, __shfl_xor(m, 4));
      m = fmaxf(m, __shfl_xor(m, 8));
      float s0 = 0.f;
#pragma unroll
      for (int nt = 0; nt < 4; nt++) {
        float e = exp2f((sacc[nt][r] - m) * 1.4426950408889634f);
        sacc[nt][r] = e; s0 += e;
      }
      s0 += __shfl_xor(s0, 1);
      s0 += __shfl_xor(s0, 2);
      s0 += __shfl_xor(s0, 4);
      s0 += __shfl_xor(s0, 8);
      sm[r] = s0;
    }
#pragma unroll
    for (int nt = 0; nt < 4; nt++)
#pragma unroll
      for (int r = 0; r < 4; r++)
        Ps[(trow + r) * 72 + nt * 16 + lane16] = f2bf(sacc[nt][r]);
    fx4 o0 = {0.f, 0.f, 0.f, 0.f}, o1 = {0.f, 0.f, 0.f, 0.f};
#pragma unroll
    for (int ks2 = 0; ks2 < 2; ks2++) {
      const bf16x8 pa = ld8(&Ps[(w * 16 + lane16) * 72 + ks2 * 32 + quad * 8]);
      const bf16x8 v0 = ld8(&VT[(lane16) * 72 + ks2 * 32 + quad * 8]);
      const bf16x8 v1 = ld8(&VT[(16 + lane16) * 72 + ks2 * 32 + quad * 8]);
      o0 = mfma16(pa, v0, o0);
      o1 = mfma16(pa, v1, o1);
    }
#pragma unroll
    for (int r = 0; r < 4; r++) {
      const float inv = 1.0f / sm[r];
      Qs[(trow + r) * 200 + h * 32 + lane16] = f2bf(o0[r] * inv);
      Qs[(trow + r) * 200 + h * 32 + 16 + lane16] = f2bf(o1[r] * inv);
    }
  }
  __syncthreads();

  bf16x8 ofr[4][6];
#pragma unroll
  for (int m = 0; m < 4; m++)
#pragma unroll
    for (int k = 0; k < 6; k++)
      ofr[m][k] = ld8(&Qs[(m * 16 + lane16) * 200 + k * 32 + quad * 8]);

  uint16_t* yb = y_attn + (size_t)b * HW_ * C_;
  uint32_t obase[4][4];
#pragma unroll
  for (int m = 0; m < 4; m++)
#pragma unroll
    for (int r = 0; r < 4; r++) {
      const int tok = m * 16 + quad * 4 + r;
      obase[m][r] = (uint32_t)(((wh * 8 + (tok >> 3)) * W_ + ww * 8 + (tok & 7)) * C_);
    }
#pragma unroll
  for (int j = 0; j < 3; j++) {
    const int nt = w + 4 * j;
    const uint16_t* bp = proj_wt + (nt * 16 + lane16) * C_ + quad * 8;
    bf16x8 bfr[6];
#pragma unroll
    for (int k = 0; k < 6; k++) bfr[k] = ld8(bp + k * 32);
    fx4 acc[4];
#pragma unroll
    for (int m = 0; m < 4; m++) acc[m] = fx4{0.f, 0.f, 0.f, 0.f};
#pragma unroll
    for (int k = 0; k < 6; k++)
#pragma unroll
      for (int m = 0; m < 4; m++) acc[m] = mfma16(ofr[m][k], bfr[k], acc[m]);
    const float pb = proj_b[nt * 16 + lane16];
    float cs = 0.f;
#pragma unroll
    for (int m = 0; m < 4; m++)
#pragma unroll
      for (int r = 0; r < 4; r++) {
        const float v = acc[m][r] + pb;
        yb[obase[m][r] + nt * 16 + lane16] = f2bf(v);
        cs += v;
      }
    cs += __shfl_xor(cs, 16);
    cs += __shfl_xor(cs, 32);
    if (l < 16) part[(size_t)wg * 192 + nt * 16 + lane16] = cs;
  }
}

// ---------------- K3: gap reduce + channel-attention scale s[b][o] ----------------
__global__ __launch_bounds__(768) void ca_s_kernel(const float* __restrict__ part,
                                                   const float* __restrict__ ca_w,
                                                   const float* __restrict__ ca_b,
                                                   float* __restrict__ sbuf) {
  int b = blockIdx.x;
  int t = threadIdx.x;
  __shared__ float red[768];
  __shared__ float gap[192];
  int g = t / 192, c = t - g * 192;
  float s = 0.f;
#pragma unroll 8
  for (int i = g; i < 1024; i += 4) s += part[((size_t)b * 1024 + i) * 192 + c];
  red[t] = s;
  __syncthreads();
  if (t < 192)
    gap[t] = (red[t] + red[t + 192] + red[t + 384] + red[t + 576]) * (1.0f / 65536.0f);
  __syncthreads();
  if (t < 192) {
    float acc = ca_b[t];
#pragma unroll 8
    for (int c2 = 0; c2 < 192; c2++) acc += gap[c2] * ca_w[t * 192 + c2];
    sbuf[b * 192 + t] = acc;
  }
}

// ---------------- K4: fused resid + LN2 + MLP + recomputed residual -> out ----------------
// 512 threads (8 waves), 64 pixels/block, 3 blocks/CU (54 KB LDS, <=80 VGPR target).
__global__ __launch_bounds__(512, 6) void fused_mlp(
    const float* __restrict__ x, const uint16_t* __restrict__ y_attn,
    const float* __restrict__ sbuf,
    const uint16_t* __restrict__ fc1_wt, const float* __restrict__ b1f,
    const uint16_t* __restrict__ fc2_wt, const float* __restrict__ fc2_b,
    float* __restrict__ out) {
  __shared__ __attribute__((aligned(16))) char smem[192 * 66 * 4];  // tileXR | hbuf | ftile
  __shared__ float red[512];
  __shared__ float mus[128];
  __shared__ float sarr[192];
  float* tileXR = (float*)smem;          // [192][66] f32
  uint16_t* hbuf = (uint16_t*)smem;      // [64][392] bf16 (aliased after barrier)
  float* ftile = (float*)smem;           // [192][66] f32 (aliased after barrier)
  const int wg = blockIdx.x;
  const int b = wg >> 10, hw0 = (wg & 1023) << 6;
  const int t = threadIdx.x;
  const int w = t >> 6, l = t & 63;
  const int lane16 = l & 15, quad = l >> 4;

  if (t < 192) sarr[t] = sbuf[b * 192 + t];

  // phase 1: x -> tileXR (float2 coalesced)
  const float* xb = x + (size_t)b * CHW + hw0;
#pragma unroll
  for (int i = 0; i < 12; i++) {
    int id = i * 512 + t;
    int c = id >> 5, p2 = id & 31;
    float2 v = *reinterpret_cast<const float2*>(xb + (size_t)c * HW_ + p2 * 2);
    *reinterpret_cast<float2*>(&tileXR[c * 66 + p2 * 2]) = v;
  }
  __syncthreads();

  // phase 2: tileXR += s[c] * y_attn (token-major ld8)
  {
    const int p = t & 63, qb = (t >> 6) * 3;
    const uint16_t* yr = y_attn + ((size_t)(b * HW_ + hw0 + p)) * C_;
#pragma unroll
    for (int i = 0; i < 3; i++) {
      int q = qb + i;
      u16x8 uv = __builtin_bit_cast(u16x8, ld8(yr + q * 8));
#pragma unroll
      for (int j = 0; j < 8; j++) {
        int c = q * 8 + j;
        tileXR[c * 66 + p] += sarr[c] * bf2f(uv[j]);
      }
    }
  }
  __syncthreads();

  // phase 3: LN2 stats (first 4 waves only)
  if (t < 256) {
    int p = t & 63, g = t >> 6;
    float s = 0.f, sq = 0.f;
#pragma unroll 8
    for (int c = g * 48; c < g * 48 + 48; c++) {
      float v = tileXR[c * 66 + p];
      s += v; sq += v * v;
    }
    red[g * 64 + p] = s;
    red[256 + g * 64 + p] = sq;
  }
  __syncthreads();
  if (t < 64) {
    float ss = red[t] + red[64 + t] + red[128 + t] + red[192 + t];
    float qq = red[256 + t] + red[320 + t] + red[384 + t] + red[448 + t];
    float m = ss * (1.0f / C_);
    float var = qq * (1.0f / C_) - m * m;
    mus[t] = m;
    mus[64 + t] = rsqrtf(var + 1e-6f);
  }
  __syncthreads();

  // phase 4: normalize own m-tile -> A-fragments in registers
  // (n2w/n2b folded into fc1_wt/b1f in prep -> A = (xr-mu)*rsig exactly)
  bf16x8 afr[6];
  const int m1 = w & 3;
  {
    const int p = m1 * 16 + lane16;
    const float mu = mus[p], rs = mus[64 + p];
#pragma unroll
    for (int k = 0; k < 6; k++) {
      uint32_t u0, u1, u2, u3;
      {
        int c = k * 32 + quad * 8;
        float a0 = (tileXR[(c + 0) * 66 + p] - mu) * rs;
        float a1 = (tileXR[(c + 1) * 66 + p] - mu) * rs;
        float a2 = (tileXR[(c + 2) * 66 + p] - mu) * rs;
        float a3 = (tileXR[(c + 3) * 66 + p] - mu) * rs;
        float a4 = (tileXR[(c + 4) * 66 + p] - mu) * rs;
        float a5 = (tileXR[(c + 5) * 66 + p] - mu) * rs;
        float a6 = (tileXR[(c + 6) * 66 + p] - mu) * rs;
        float a7 = (tileXR[(c + 7) * 66 + p] - mu) * rs;
        u0 = pk2(a0, a1); u1 = pk2(a2, a3); u2 = pk2(a4, a5); u3 = pk2(a6, a7);
      }
      uint4 uv = {u0, u1, u2, u3};
      afr[k] = __builtin_bit_cast(bf16x8, uv);
    }
  }
  __syncthreads();   // tileXR reads done; smem becomes hbuf

  // phase 5: GEMM1 (swapped operands -> D[f][tok], lane holds 4 consecutive f)
  // wave: m = w&3, nt = (w>>2)*12 + j
  {
    const int ntb = (w >> 2) * 12;
#pragma unroll 4
    for (int j = 0; j < 12; j++) {
      const int nt = ntb + j;
      const uint16_t* bp = fc1_wt + (nt * 16 + lane16) * C_ + quad * 8;
      bf16x8 bfr[6];
#pragma unroll
      for (int k = 0; k < 6; k++) bfr[k] = ld8(bp + k * 32);
      fx4 acc = {0.f, 0.f, 0.f, 0.f};
#pragma unroll
      for (int k = 0; k < 6; k++) acc = mfma16(bfr[k], afr[k], acc);
      const fx4 b4 = *reinterpret_cast<const fx4*>(b1f + nt * 16 + quad * 4);
      float g0 = gelu_f(acc[0] + b4[0]);
      float g1 = gelu_f(acc[1] + b4[1]);
      float g2 = gelu_f(acc[2] + b4[2]);
      float g3 = gelu_f(acc[3] + b4[3]);
      uint2 wv = {pk2(g0, g1), pk2(g2, g3)};
      *reinterpret_cast<uint2*>(&hbuf[(m1 * 16 + lane16) * 392 + nt * 16 + quad * 4]) = wv;
    }
  }
  __syncthreads();   // hidden features cross-wave

  // phase 6: GEMM2 (unswapped -> D[tok][o]); wave: m in {2*(w>>2), +1}, nt2 = (w&3)*3 + j
  const int mh2 = w >> 2;
  const int ntr2 = w & 3;
  fx4 acc2[3][2];
#pragma unroll
  for (int j = 0; j < 3; j++)
#pragma unroll
    for (int mi = 0; mi < 2; mi++) acc2[j][mi] = fx4{0.f, 0.f, 0.f, 0.f};
#pragma unroll
  for (int kc = 0; kc < 4; kc++) {
    bf16x8 ha[2][3];
#pragma unroll
    for (int mi = 0; mi < 2; mi++)
#pragma unroll
      for (int kk = 0; kk < 3; kk++)
        ha[mi][kk] = ld8(&hbuf[((mh2 * 2 + mi) * 16 + lane16) * 392 + kc * 96 + kk * 32 + quad * 8]);
#pragma unroll
    for (int j = 0; j < 3; j++) {
      const int nt2 = ntr2 * 3 + j;
      const uint16_t* bp = fc2_wt + (nt2 * 16 + lane16) * HID_ + kc * 96 + quad * 8;
#pragma unroll
      for (int kk = 0; kk < 3; kk++) {
        const bf16x8 bb = ld8(bp + kk * 32);
#pragma unroll
        for (int mi = 0; mi < 2; mi++)
          acc2[j][mi] = mfma16(ha[mi][kk], bb, acc2[j][mi]);
      }
    }
  }
  __syncthreads();   // hbuf dead; ftile aliases

  // phase 7: y2 + bias -> ftile[o][tok]
#pragma unroll
  for (int j = 0; j < 3; j++) {
    const int nt2 = ntr2 * 3 + j;
    const float bias = fc2_b[nt2 * 16 + lane16];
#pragma unroll
    for (int mi = 0; mi < 2; mi++) {
      float* fp = &ftile[(nt2 * 16 + lane16) * 66 + (mh2 * 2 + mi) * 16 + quad * 4];
      float2 aa = {acc2[j][mi][0] + bias, acc2[j][mi][1] + bias};
      float2 bb2 = {acc2[j][mi][2] + bias, acc2[j][mi][3] + bias};
      *reinterpret_cast<float2*>(fp) = aa;
      *reinterpret_cast<float2*>(fp + 2) = bb2;
    }
  }
  __syncthreads();

  // phase 8: ftile += s[c] * y_attn (re-read, L2/L3-hot)
  {
    const int p = t & 63, qb = (t >> 6) * 3;
    const uint16_t* yr = y_attn + ((size_t)(b * HW_ + hw0 + p)) * C_;
#pragma unroll
    for (int i = 0; i < 3; i++) {
      int q = qb + i;
      u16x8 uv = __builtin_bit_cast(u16x8, ld8(yr + q * 8));
#pragma unroll
      for (int j = 0; j < 8; j++) {
        int c = q * 8 + j;
        ftile[c * 66 + p] += sarr[c] * bf2f(uv[j]);
      }
    }
  }
  __syncthreads();

  // phase 9: out = x + ftile (float2 coalesced)
  float* ob = out + (size_t)b * CHW + hw0;
#pragma unroll
  for (int i = 0; i < 12; i++) {
    int id = i * 512 + t;
    int c = id >> 5, p2 = id & 31;
    float2 xv = *reinterpret_cast<const float2*>(xb + (size_t)c * HW_ + p2 * 2);
    float2 fv = *reinterpret_cast<const float2*>(&ftile[c * 66 + p2 * 2]);
    float2 ov = {xv.x + fv.x, xv.y + fv.y};
    *reinterpret_cast<float2*>(ob + (size_t)c * HW_ + p2 * 2) = ov;
  }
}

extern "C" void kernel_launch(void* const* d_in, const int* in_sizes, int n_in,
                              void* d_out, int out_size, void* d_ws, size_t ws_size,
                              hipStream_t stream) {
  const float* x      = (const float*)d_in[0];
  const float* n1w    = (const float*)d_in[1];
  const float* n1b    = (const float*)d_in[2];
  const float* qkv_w  = (const float*)d_in[3];
  const float* qkv_b  = (const float*)d_in[4];
  const float* proj_w = (const float*)d_in[5];
  const float* proj_b = (const float*)d_in[6];
  const float* rpb    = (const float*)d_in[7];
  const float* ca_w   = (const float*)d_in[8];
  const float* ca_b   = (const float*)d_in[9];
  const float* n2w    = (const float*)d_in[10];
  const float* n2b    = (const float*)d_in[11];
  const float* fc1_w  = (const float*)d_in[12];
  const float* fc1_b  = (const float*)d_in[13];
  const float* fc2_w  = (const float*)d_in[14];
  const float* fc2_b  = (const float*)d_in[15];
  float* out = (float*)d_out;

  char* ws = (char*)d_ws;
  uint16_t* y_tok   = (uint16_t*)(ws + 0);           // 50331648 B
  uint16_t* y_attn  = (uint16_t*)(ws + 50331648);    // 50331648 B
  float*    mu      = (float*)   (ws + 100663296);   // 524288 B
  float*    rsig    = (float*)   (ws + 101187584);   // 524288 B
  uint16_t* qkv_wt  = (uint16_t*)(ws + 101711872);   // 221184 B
  uint16_t* proj_wt = (uint16_t*)(ws + 101933056);   // 73728 B
  uint16_t* fc1_wt  = (uint16_t*)(ws + 102006784);   // 147456 B
  uint16_t* fc2_wt  = (uint16_t*)(ws + 102154240);   // 147456 B
  float*    rpbb    = (float*)   (ws + 102301696);   // 98304 B
  float*    part    = (float*)   (ws + 102400000);   // 1572864 B
  float*    sbuf    = (float*)   (ws + 103972864);   // 1536 B
  float*    b1f     = (float*)   (ws + 103974400);   // 1536 B (folded fc1 bias)

  hipLaunchKernelGGL(prep_kernel, dim3(1250), dim3(256), 0, stream,
                     qkv_w, proj_w, fc1_w, fc2_w, rpb, n2w, n2b, fc1_b,
                     qkv_wt, proj_wt, fc1_wt, fc2_wt, rpbb, b1f);
  hipLaunchKernelGGL(ln1_stats, dim3(512), dim3(256), 0, stream, x, mu, rsig);
  hipLaunchKernelGGL(ln1_apply_kernel, dim3(2048), dim3(256), 0, stream,
                     x, mu, rsig, n1w, n1b, y_tok);
  hipLaunchKernelGGL(attn_kernel, dim3(2048), dim3(256), 0, stream,
                     y_tok, qkv_wt, qkv_b, proj_wt, proj_b, rpbb, y_attn, part);
  hipLaunchKernelGGL(ca_s_kernel, dim3(2), dim3(768), 0, stream, part, ca_w, ca_b, sbuf);
  hipLaunchKernelGGL(fused_mlp, dim3(2048), dim3(512), 0, stream,
                     x, y_attn, sbuf, fc1_wt, b1f, fc2_wt, fc2_b, out);
}

// Round 3
// 617.774 us; speedup vs baseline: 1.1130x; 1.1130x over previous
//
#include <hip/hip_runtime.h>
#include <hip/hip_bf16.h>
#include <stdint.h>

#define C_   192
#define H_   256
#define W_   256
#define HW_  65536
#define CHW  12582912
#define NH_  6
#define HID_ 384

typedef __attribute__((ext_vector_type(8))) __bf16 bf16x8;
typedef __attribute__((ext_vector_type(8))) uint16_t u16x8;
typedef __attribute__((ext_vector_type(4))) float  fx4;

__device__ __forceinline__ uint16_t f2bf(float f) {
  uint32_t u = __builtin_bit_cast(uint32_t, f);
  u += 0x7fffu + ((u >> 16) & 1u);
  return (uint16_t)(u >> 16);
}
__device__ __forceinline__ float bf2f(uint16_t h) {
  uint32_t u = ((uint32_t)h) << 16;
  return __builtin_bit_cast(float, u);
}
__device__ __forceinline__ uint32_t pk2(float a, float b) {
  return (uint32_t)f2bf(a) | ((uint32_t)f2bf(b) << 16);
}
__device__ __forceinline__ bf16x8 ld8(const uint16_t* p) {
  uint4 v = *reinterpret_cast<const uint4*>(p);
  return __builtin_bit_cast(bf16x8, v);
}
__device__ __forceinline__ fx4 mfma16(bf16x8 a, bf16x8 b, fx4 c) {
  return __builtin_amdgcn_mfma_f32_16x16x32_bf16(a, b, c, 0, 0, 0);
}
// tanh-form GELU: 0.5v(1+tanh(0.79788456(v+0.044715 v^3)))
// exp2-based; max |err| vs erf-GELU ~3e-4 (<< bf16 rounding of hidden acts).
__device__ __forceinline__ float gelu_f(float v) {
  float c2 = v * v;
  float u = __builtin_fmaf(c2, 0.044715f, 1.0f) * v;   // v + 0.044715 v^3
  float e = exp2f(u * 2.3022084f);                     // exp(2*0.79788456*u)
  float th = 1.0f - 2.0f * __builtin_amdgcn_rcpf(1.0f + e);
  float hv = 0.5f * v;
  return __builtin_fmaf(hv, th, hv);
}

// ---------------- K0: weight prep (transpose to bf16 B-fragment layout) ----------------
// fc1 weights get LN2's n2w folded in; b1f = fc1_b + n2b . fc1_w (exact LN-affine fold).
__global__ __launch_bounds__(256) void prep_kernel(
    const float* __restrict__ qkv_w, const float* __restrict__ proj_w,
    const float* __restrict__ fc1_w, const float* __restrict__ fc2_w,
    const float* __restrict__ rpb, const float* __restrict__ n2w,
    const float* __restrict__ n2b, const float* __restrict__ fc1_b,
    uint16_t* __restrict__ qkv_wt, uint16_t* __restrict__ proj_wt,
    uint16_t* __restrict__ fc1_wt, uint16_t* __restrict__ fc2_wt,
    float* __restrict__ rpbb, float* __restrict__ b1f) {
  int tid = blockIdx.x * 256 + threadIdx.x;
  if (tid < 576 * 192) {                       // qkv_wt[f][k] = qkv_w[k][f]
    int f = tid / 192, k = tid % 192;
    qkv_wt[tid] = f2bf(qkv_w[k * 576 + f]);
  }
  int t1 = tid - 576 * 192;
  if (t1 >= 0 && t1 < 192 * 192) {             // proj_wt[f][k]
    int f = t1 / 192, k = t1 % 192;
    proj_wt[t1] = f2bf(proj_w[k * 192 + f]);
  }
  int t2 = t1 - 192 * 192;
  if (t2 >= 0 && t2 < 384 * 192) {             // fc1_wt[f][k] = fc1_w[k][f]*n2w[k]
    int f = t2 / 192, k = t2 % 192;
    fc1_wt[t2] = f2bf(fc1_w[k * 384 + f] * n2w[k]);
  }
  int t3 = t2 - 384 * 192;
  if (t3 >= 0 && t3 < 192 * 384) {             // fc2_wt[o][k]
    int f = t3 / 384, k = t3 % 384;
    fc2_wt[t3] = f2bf(fc2_w[k * 192 + f]);
  }
  int t4 = t3 - 192 * 384;
  if (t4 >= 0 && t4 < 6 * 64 * 64) {           // rpbb[h][n][m]
    int h = t4 / 4096, nm = t4 % 4096, n = nm / 64, m = nm % 64;
    int yn = n >> 3, xn = n & 7, ym = m >> 3, xm = m & 7;
    int idx = (yn - ym + 7) * 15 + (xn - xm + 7);
    rpbb[t4] = rpb[idx * NH_ + h];
  }
  int t5 = t4 - 6 * 64 * 64;
  if (t5 >= 0 && t5 < 384) {                   // folded fc1 bias
    float acc = fc1_b[t5];
    for (int c = 0; c < 192; c++) acc = __builtin_fmaf(n2b[c], fc1_w[c * 384 + t5], acc);
    b1f[t5] = acc;
  }
}

// ---------------- K1a: LN1 stats (mu, rsig per pixel) ----------------
__global__ __launch_bounds__(256) void ln1_stats(const float* __restrict__ x,
                                                 float* __restrict__ mu,
                                                 float* __restrict__ rsig) {
  int t = blockIdx.x * 256 + threadIdx.x;   // (b,hw)
  int b = t >> 16, hw = t & 65535;
  const float* xp = x + (size_t)b * CHW + hw;
  float s = 0.f, sq = 0.f;
#pragma unroll 8
  for (int c = 0; c < C_; c++) {
    float v = xp[(size_t)c * HW_];
    s += v; sq += v * v;
  }
  float m = s * (1.0f / C_);
  float var = sq * (1.0f / C_) - m * m;
  mu[t] = m;
  rsig[t] = rsqrtf(var + 1e-6f);
}

// ---------------- K1b: apply LN1 + roll-reinterpret shuffle + transpose -> token-major bf16 --
__global__ __launch_bounds__(256) void ln1_apply_kernel(
    const float* __restrict__ x, const float* __restrict__ mu, const float* __restrict__ rsig,
    const float* __restrict__ n1w, const float* __restrict__ n1b,
    uint16_t* __restrict__ y_tok) {
  __shared__ __attribute__((aligned(16))) uint16_t tile[192 * 66];
  int wg = blockIdx.x;
  int b = wg >> 10, hw0 = (wg & 1023) << 6;
  int t = threadIdx.x;
  const float* xb = x + (size_t)b * CHW;
  const float* mub = mu + b * HW_;
  const float* rsb = rsig + b * HW_;
#pragma unroll 4
  for (int it = 0; it < 48; it++) {
    int id = it * 256 + t;
    int ca = id >> 6, pp = id & 63;
    int g = ca * 65536 + hw0 + pp;
    int h2 = g / 49152;
    int r = g - h2 * 49152;
    int w2 = r / 192;
    int c2 = r - w2 * 192;
    int f = ((h2 + 4) & 255) * 49152 + ((w2 + 4) & 255) * 192 + c2;
    int cnat = f >> 16;
    int hwn = f & 65535;
    float v = (xb[f] - mub[hwn]) * rsb[hwn] * n1w[cnat] + n1b[cnat];
    tile[ca * 66 + pp] = f2bf(v);
  }
  __syncthreads();
  uint16_t* yb = y_tok + ((size_t)(b * HW_ + hw0)) * C_;
#pragma unroll 4
  for (int it = 0; it < 48; it++) {
    int id = it * 256 + t;
    int pp = id / 192, ca = id - pp * 192;
    yb[id] = tile[ca * 66 + pp];
  }
}

// ---------------- K2: fused window attention + fused GAP partials ----------------
__global__ __launch_bounds__(256, 2) void attn_kernel(
    const uint16_t* __restrict__ y_tok, const uint16_t* __restrict__ qkv_wt,
    const float* __restrict__ qkv_b, const uint16_t* __restrict__ proj_wt,
    const float* __restrict__ proj_b, const float* __restrict__ rpbb,
    uint16_t* __restrict__ y_attn, float* __restrict__ part) {
  __shared__ __attribute__((aligned(16))) uint16_t Qs[64 * 200]; // Q, later O
  __shared__ __attribute__((aligned(16))) uint16_t Ks[64 * 200];
  __shared__ __attribute__((aligned(16))) uint16_t VT[32 * 72];
  __shared__ __attribute__((aligned(16))) uint16_t Ps[64 * 72];
  const int wg = blockIdx.x;
  const int b = wg >> 10, wid = wg & 1023;
  const int wh = wid >> 5, ww = wid & 31;
  const int t = threadIdx.x;
  const int w = t >> 6, l = t & 63;
  const int lane16 = l & 15, quad = l >> 4;
  const int trow = w * 16 + quad * 4;

  bf16x8 afr[4][6];
#pragma unroll
  for (int m = 0; m < 4; m++) {
    const int tok = m * 16 + lane16;
    const uint16_t* ap = y_tok +
        ((size_t)(b * HW_ + (wh * 8 + (tok >> 3)) * W_ + ww * 8 + (tok & 7))) * C_ + quad * 8;
#pragma unroll
    for (int k = 0; k < 6; k++) afr[m][k] = ld8(ap + k * 32);
  }

  const float scale = 0.17677669529663687f;
  uint32_t vpack[3][4][2];

#pragma unroll
  for (int j = 0; j < 3; j++) {
    const int nt = w + 4 * j;
    const uint16_t* bp = qkv_wt + (nt * 16 + lane16) * C_ + quad * 8;
    bf16x8 bfr[6];
#pragma unroll
    for (int k = 0; k < 6; k++) bfr[k] = ld8(bp + k * 32);
    fx4 acc[4];
#pragma unroll
    for (int m = 0; m < 4; m++) acc[m] = fx4{0.f, 0.f, 0.f, 0.f};
#pragma unroll
    for (int k = 0; k < 6; k++)
#pragma unroll
      for (int m = 0; m < 4; m++) acc[m] = mfma16(afr[m][k], bfr[k], acc[m]);
    const int f = nt * 16 + lane16;
    const float bias = qkv_b[f];
#pragma unroll
    for (int m = 0; m < 4; m++)
#pragma unroll
      for (int r = 0; r < 4; r++)
        Qs[(m * 16 + quad * 4 + r) * 200 + f] = f2bf((acc[m][r] + bias) * scale);
  }
#pragma unroll
  for (int j = 3; j < 6; j++) {
    const int nt = w + 4 * j;
    const uint16_t* bp = qkv_wt + (nt * 16 + lane16) * C_ + quad * 8;
    bf16x8 bfr[6];
#pragma unroll
    for (int k = 0; k < 6; k++) bfr[k] = ld8(bp + k * 32);
    fx4 acc[4];
#pragma unroll
    for (int m = 0; m < 4; m++) acc[m] = fx4{0.f, 0.f, 0.f, 0.f};
#pragma unroll
    for (int k = 0; k < 6; k++)
#pragma unroll
      for (int m = 0; m < 4; m++) acc[m] = mfma16(afr[m][k], bfr[k], acc[m]);
    const int f = nt * 16 + lane16;
    const float bias = qkv_b[f];
#pragma unroll
    for (int m = 0; m < 4; m++)
#pragma unroll
      for (int r = 0; r < 4; r++)
        Ks[(m * 16 + quad * 4 + r) * 200 + (f - 192)] = f2bf(acc[m][r] + bias);
  }
#pragma unroll
  for (int j = 6; j < 9; j++) {
    const int nt = w + 4 * j;
    const uint16_t* bp = qkv_wt + (nt * 16 + lane16) * C_ + quad * 8;
    bf16x8 bfr[6];
#pragma unroll
    for (int k = 0; k < 6; k++) bfr[k] = ld8(bp + k * 32);
    fx4 acc[4];
#pragma unroll
    for (int m = 0; m < 4; m++) acc[m] = fx4{0.f, 0.f, 0.f, 0.f};
#pragma unroll
    for (int k = 0; k < 6; k++)
#pragma unroll
      for (int m = 0; m < 4; m++) acc[m] = mfma16(afr[m][k], bfr[k], acc[m]);
    const float bias = qkv_b[nt * 16 + lane16];
    const int jv = j - 6;
#pragma unroll
    for (int m = 0; m < 4; m++) {
      vpack[jv][m][0] = pk2(acc[m][0] + bias, acc[m][1] + bias);
      vpack[jv][m][1] = pk2(acc[m][2] + bias, acc[m][3] + bias);
    }
  }

  const bool whe = (wh == 31), wwe = (ww == 31);

  for (int h = 0; h < 6; h++) {
    __syncthreads();
    {
      const int vt0 = 2 * h, vt1 = 2 * h + 1;
      if (w == (vt0 & 3)) {
        const int jv = vt0 >> 2;
#pragma unroll
        for (int m = 0; m < 4; m++) {
          uint2 vv; vv.x = vpack[jv][m][0]; vv.y = vpack[jv][m][1];
          *reinterpret_cast<uint2*>(&VT[lane16 * 72 + m * 16 + quad * 4]) = vv;
        }
      }
      if (w == (vt1 & 3)) {
        const int jv = vt1 >> 2;
#pragma unroll
        for (int m = 0; m < 4; m++) {
          uint2 vv; vv.x = vpack[jv][m][0]; vv.y = vpack[jv][m][1];
          *reinterpret_cast<uint2*>(&VT[(16 + lane16) * 72 + m * 16 + quad * 4]) = vv;
        }
      }
    }
    __syncthreads();

    const bf16x8 qa = ld8(&Qs[(w * 16 + lane16) * 200 + h * 32 + quad * 8]);
    fx4 sacc[4];
#pragma unroll
    for (int nt = 0; nt < 4; nt++) {
      const bf16x8 kb = ld8(&Ks[(nt * 16 + lane16) * 200 + h * 32 + quad * 8]);
      fx4 z = {0.f, 0.f, 0.f, 0.f};
      sacc[nt] = mfma16(qa, kb, z);
    }
    const float* rb = rpbb + h * 4096;
#pragma unroll
    for (int nt = 0; nt < 4; nt++) {
      const int ct = nt * 16 + lane16;
      const bool rbc = whe && ((ct >> 3) >= 4);
      const bool cbc = wwe && ((ct & 7) >= 4);
#pragma unroll
      for (int r = 0; r < 4; r++) {
        const int rt = trow + r;
        const bool rbr = whe && ((rt >> 3) >= 4);
        const bool cbr = wwe && ((rt & 7) >= 4);
        float v = sacc[nt][r] + rb[rt * 64 + ct];
        if (rbr != rbc || cbr != cbc) v -= 100.f;
        sacc[nt][r] = v;
      }
    }
    float sm[4];
#pragma unroll
    for (int r = 0; r < 4; r++) {
      float m = fmaxf(fmaxf(sacc[0][r], sacc[1][r]), fmaxf(sacc[2][r], sacc[3][r]));
      m = fmaxf(m, __shfl_xor(m, 1));
      m = fmaxf(m, __shfl_xor(m, 2));
      m = fmaxf(m, __shfl_xor(m, 4));
      m = fmaxf(m, __shfl_xor(m, 8));
      float s0 = 0.f;
#pragma unroll
      for (int nt = 0; nt < 4; nt++) {
        float e = exp2f((sacc[nt][r] - m) * 1.4426950408889634f);
        sacc[nt][r] = e; s0 += e;
      }
      s0 += __shfl_xor(s0, 1);
      s0 += __shfl_xor(s0, 2);
      s0 += __shfl_xor(s0, 4);
      s0 += __shfl_xor(s0, 8);
      sm[r] = s0;
    }
#pragma unroll
    for (int nt = 0; nt < 4; nt++)
#pragma unroll
      for (int r = 0; r < 4; r++)
        Ps[(trow + r) * 72 + nt * 16 + lane16] = f2bf(sacc[nt][r]);
    fx4 o0 = {0.f, 0.f, 0.f, 0.f}, o1 = {0.f, 0.f, 0.f, 0.f};
#pragma unroll
    for (int ks2 = 0; ks2 < 2; ks2++) {
      const bf16x8 pa = ld8(&Ps[(w * 16 + lane16) * 72 + ks2 * 32 + quad * 8]);
      const bf16x8 v0 = ld8(&VT[(lane16) * 72 + ks2 * 32 + quad * 8]);
      const bf16x8 v1 = ld8(&VT[(16 + lane16) * 72 + ks2 * 32 + quad * 8]);
      o0 = mfma16(pa, v0, o0);
      o1 = mfma16(pa, v1, o1);
    }
#pragma unroll
    for (int r = 0; r < 4; r++) {
      const float inv = 1.0f / sm[r];
      Qs[(trow + r) * 200 + h * 32 + lane16] = f2bf(o0[r] * inv);
      Qs[(trow + r) * 200 + h * 32 + 16 + lane16] = f2bf(o1[r] * inv);
    }
  }
  __syncthreads();

  bf16x8 ofr[4][6];
#pragma unroll
  for (int m = 0; m < 4; m++)
#pragma unroll
    for (int k = 0; k < 6; k++)
      ofr[m][k] = ld8(&Qs[(m * 16 + lane16) * 200 + k * 32 + quad * 8]);

  uint16_t* yb = y_attn + (size_t)b * HW_ * C_;
  uint32_t obase[4][4];
#pragma unroll
  for (int m = 0; m < 4; m++)
#pragma unroll
    for (int r = 0; r < 4; r++) {
      const int tok = m * 16 + quad * 4 + r;
      obase[m][r] = (uint32_t)(((wh * 8 + (tok >> 3)) * W_ + ww * 8 + (tok & 7)) * C_);
    }
#pragma unroll
  for (int j = 0; j < 3; j++) {
    const int nt = w + 4 * j;
    const uint16_t* bp = proj_wt + (nt * 16 + lane16) * C_ + quad * 8;
    bf16x8 bfr[6];
#pragma unroll
    for (int k = 0; k < 6; k++) bfr[k] = ld8(bp + k * 32);
    fx4 acc[4];
#pragma unroll
    for (int m = 0; m < 4; m++) acc[m] = fx4{0.f, 0.f, 0.f, 0.f};
#pragma unroll
    for (int k = 0; k < 6; k++)
#pragma unroll
      for (int m = 0; m < 4; m++) acc[m] = mfma16(ofr[m][k], bfr[k], acc[m]);
    const float pb = proj_b[nt * 16 + lane16];
    float cs = 0.f;
#pragma unroll
    for (int m = 0; m < 4; m++)
#pragma unroll
      for (int r = 0; r < 4; r++) {
        const float v = acc[m][r] + pb;
        yb[obase[m][r] + nt * 16 + lane16] = f2bf(v);
        cs += v;
      }
    cs += __shfl_xor(cs, 16);
    cs += __shfl_xor(cs, 32);
    if (l < 16) part[(size_t)wg * 192 + nt * 16 + lane16] = cs;
  }
}

// ---------------- K3: gap reduce + channel-attention scale s[b][o] ----------------
__global__ __launch_bounds__(768) void ca_s_kernel(const float* __restrict__ part,
                                                   const float* __restrict__ ca_w,
                                                   const float* __restrict__ ca_b,
                                                   float* __restrict__ sbuf) {
  int b = blockIdx.x;
  int t = threadIdx.x;
  __shared__ float red[768];
  __shared__ float gap[192];
  int g = t / 192, c = t - g * 192;
  float s = 0.f;
#pragma unroll 8
  for (int i = g; i < 1024; i += 4) s += part[((size_t)b * 1024 + i) * 192 + c];
  red[t] = s;
  __syncthreads();
  if (t < 192)
    gap[t] = (red[t] + red[t + 192] + red[t + 384] + red[t + 576]) * (1.0f / 65536.0f);
  __syncthreads();
  if (t < 192) {
    float acc = ca_b[t];
#pragma unroll 8
    for (int c2 = 0; c2 < 192; c2++) acc += gap[c2] * ca_w[t * 192 + c2];
    sbuf[b * 192 + t] = acc;
  }
}

// ---------------- K4: fused resid + LN2 + MLP + recomputed residual -> out ----------------
// 512 threads (8 waves), 64 pixels/block.
// __launch_bounds__(512, 4): 4 waves/EU -> VGPR cap ~128 (NOT 6 -> cap ~85, which
// forced scratch spills in round 2: VGPR_Count=40, WRITE_SIZE 3x output).
__global__ __launch_bounds__(512, 4) void fused_mlp(
    const float* __restrict__ x, const uint16_t* __restrict__ y_attn,
    const float* __restrict__ sbuf,
    const uint16_t* __restrict__ fc1_wt, const float* __restrict__ b1f,
    const uint16_t* __restrict__ fc2_wt, const float* __restrict__ fc2_b,
    float* __restrict__ out) {
  __shared__ __attribute__((aligned(16))) char smem[192 * 66 * 4];  // tileXR | hbuf | ftile
  __shared__ float red[512];
  __shared__ float mus[128];
  __shared__ float sarr[192];
  float* tileXR = (float*)smem;          // [192][66] f32
  uint16_t* hbuf = (uint16_t*)smem;      // [64][392] bf16 (aliased after barrier)
  float* ftile = (float*)smem;           // [192][66] f32 (aliased after barrier)
  const int wg = blockIdx.x;
  const int b = wg >> 10, hw0 = (wg & 1023) << 6;
  const int t = threadIdx.x;
  const int w = t >> 6, l = t & 63;
  const int lane16 = l & 15, quad = l >> 4;

  if (t < 192) sarr[t] = sbuf[b * 192 + t];

  // phase 1: x -> tileXR (float2 coalesced)
  const float* xb = x + (size_t)b * CHW + hw0;
#pragma unroll
  for (int i = 0; i < 12; i++) {
    int id = i * 512 + t;
    int c = id >> 5, p2 = id & 31;
    float2 v = *reinterpret_cast<const float2*>(xb + (size_t)c * HW_ + p2 * 2);
    *reinterpret_cast<float2*>(&tileXR[c * 66 + p2 * 2]) = v;
  }
  __syncthreads();

  // phase 2: tileXR += s[c] * y_attn (token-major ld8)
  {
    const int p = t & 63, qb = (t >> 6) * 3;
    const uint16_t* yr = y_attn + ((size_t)(b * HW_ + hw0 + p)) * C_;
#pragma unroll
    for (int i = 0; i < 3; i++) {
      int q = qb + i;
      u16x8 uv = __builtin_bit_cast(u16x8, ld8(yr + q * 8));
#pragma unroll
      for (int j = 0; j < 8; j++) {
        int c = q * 8 + j;
        tileXR[c * 66 + p] += sarr[c] * bf2f(uv[j]);
      }
    }
  }
  __syncthreads();

  // phase 3: LN2 stats (first 4 waves only)
  if (t < 256) {
    int p = t & 63, g = t >> 6;
    float s = 0.f, sq = 0.f;
#pragma unroll 8
    for (int c = g * 48; c < g * 48 + 48; c++) {
      float v = tileXR[c * 66 + p];
      s += v; sq += v * v;
    }
    red[g * 64 + p] = s;
    red[256 + g * 64 + p] = sq;
  }
  __syncthreads();
  if (t < 64) {
    float ss = red[t] + red[64 + t] + red[128 + t] + red[192 + t];
    float qq = red[256 + t] + red[320 + t] + red[384 + t] + red[448 + t];
    float m = ss * (1.0f / C_);
    float var = qq * (1.0f / C_) - m * m;
    mus[t] = m;
    mus[64 + t] = rsqrtf(var + 1e-6f);
  }
  __syncthreads();

  // phase 4: normalize own m-tile -> A-fragments in registers
  // (n2w/n2b folded into fc1_wt/b1f in prep -> A = (xr-mu)*rsig exactly)
  bf16x8 afr[6];
  const int m1 = w & 3;
  {
    const int p = m1 * 16 + lane16;
    const float mu = mus[p], rs = mus[64 + p];
#pragma unroll
    for (int k = 0; k < 6; k++) {
      uint32_t u0, u1, u2, u3;
      {
        int c = k * 32 + quad * 8;
        float a0 = (tileXR[(c + 0) * 66 + p] - mu) * rs;
        float a1 = (tileXR[(c + 1) * 66 + p] - mu) * rs;
        float a2 = (tileXR[(c + 2) * 66 + p] - mu) * rs;
        float a3 = (tileXR[(c + 3) * 66 + p] - mu) * rs;
        float a4 = (tileXR[(c + 4) * 66 + p] - mu) * rs;
        float a5 = (tileXR[(c + 5) * 66 + p] - mu) * rs;
        float a6 = (tileXR[(c + 6) * 66 + p] - mu) * rs;
        float a7 = (tileXR[(c + 7) * 66 + p] - mu) * rs;
        u0 = pk2(a0, a1); u1 = pk2(a2, a3); u2 = pk2(a4, a5); u3 = pk2(a6, a7);
      }
      uint4 uv = {u0, u1, u2, u3};
      afr[k] = __builtin_bit_cast(bf16x8, uv);
    }
  }
  __syncthreads();   // tileXR reads done; smem becomes hbuf

  // phase 5: GEMM1 (swapped operands -> D[f][tok], lane holds 4 consecutive f)
  // wave: m = w&3, nt = (w>>2)*12 + j
  {
    const int ntb = (w >> 2) * 12;
#pragma unroll 4
    for (int j = 0; j < 12; j++) {
      const int nt = ntb + j;
      const uint16_t* bp = fc1_wt + (nt * 16 + lane16) * C_ + quad * 8;
      bf16x8 bfr[6];
#pragma unroll
      for (int k = 0; k < 6; k++) bfr[k] = ld8(bp + k * 32);
      fx4 acc = {0.f, 0.f, 0.f, 0.f};
#pragma unroll
      for (int k = 0; k < 6; k++) acc = mfma16(bfr[k], afr[k], acc);
      const fx4 b4 = *reinterpret_cast<const fx4*>(b1f + nt * 16 + quad * 4);
      float g0 = gelu_f(acc[0] + b4[0]);
      float g1 = gelu_f(acc[1] + b4[1]);
      float g2 = gelu_f(acc[2] + b4[2]);
      float g3 = gelu_f(acc[3] + b4[3]);
      uint2 wv = {pk2(g0, g1), pk2(g2, g3)};
      *reinterpret_cast<uint2*>(&hbuf[(m1 * 16 + lane16) * 392 + nt * 16 + quad * 4]) = wv;
    }
  }
  __syncthreads();   // hidden features cross-wave

  // phase 6: GEMM2 (unswapped -> D[tok][o]); wave: m in {2*(w>>2), +1}, nt2 = (w&3)*3 + j
  // ha loaded per-kk (8 regs in flight, not 24) to stay under the VGPR cap.
  const int mh2 = w >> 2;
  const int ntr2 = w & 3;
  fx4 acc2[3][2];
#pragma unroll
  for (int j = 0; j < 3; j++)
#pragma unroll
    for (int mi = 0; mi < 2; mi++) acc2[j][mi] = fx4{0.f, 0.f, 0.f, 0.f};
#pragma unroll
  for (int kc = 0; kc < 4; kc++) {
#pragma unroll
    for (int kk = 0; kk < 3; kk++) {
      bf16x8 ha0 = ld8(&hbuf[((mh2 * 2 + 0) * 16 + lane16) * 392 + kc * 96 + kk * 32 + quad * 8]);
      bf16x8 ha1 = ld8(&hbuf[((mh2 * 2 + 1) * 16 + lane16) * 392 + kc * 96 + kk * 32 + quad * 8]);
#pragma unroll
      for (int j = 0; j < 3; j++) {
        const int nt2 = ntr2 * 3 + j;
        const bf16x8 bb = ld8(fc2_wt + (nt2 * 16 + lane16) * HID_ + kc * 96 + kk * 32 + quad * 8);
        acc2[j][0] = mfma16(ha0, bb, acc2[j][0]);
        acc2[j][1] = mfma16(ha1, bb, acc2[j][1]);
      }
    }
  }
  __syncthreads();   // hbuf dead; ftile aliases

  // phase 7: y2 + bias -> ftile[o][tok]
#pragma unroll
  for (int j = 0; j < 3; j++) {
    const int nt2 = ntr2 * 3 + j;
    const float bias = fc2_b[nt2 * 16 + lane16];
#pragma unroll
    for (int mi = 0; mi < 2; mi++) {
      float* fp = &ftile[(nt2 * 16 + lane16) * 66 + (mh2 * 2 + mi) * 16 + quad * 4];
      float2 aa = {acc2[j][mi][0] + bias, acc2[j][mi][1] + bias};
      float2 bb2 = {acc2[j][mi][2] + bias, acc2[j][mi][3] + bias};
      *reinterpret_cast<float2*>(fp) = aa;
      *reinterpret_cast<float2*>(fp + 2) = bb2;
    }
  }
  __syncthreads();

  // phase 8: ftile += s[c] * y_attn (re-read, L2/L3-hot)
  {
    const int p = t & 63, qb = (t >> 6) * 3;
    const uint16_t* yr = y_attn + ((size_t)(b * HW_ + hw0 + p)) * C_;
#pragma unroll
    for (int i = 0; i < 3; i++) {
      int q = qb + i;
      u16x8 uv = __builtin_bit_cast(u16x8, ld8(yr + q * 8));
#pragma unroll
      for (int j = 0; j < 8; j++) {
        int c = q * 8 + j;
        ftile[c * 66 + p] += sarr[c] * bf2f(uv[j]);
      }
    }
  }
  __syncthreads();

  // phase 9: out = x + ftile (float2 coalesced)
  float* ob = out + (size_t)b * CHW + hw0;
#pragma unroll
  for (int i = 0; i < 12; i++) {
    int id = i * 512 + t;
    int c = id >> 5, p2 = id & 31;
    float2 xv = *reinterpret_cast<const float2*>(xb + (size_t)c * HW_ + p2 * 2);
    float2 fv = *reinterpret_cast<const float2*>(&ftile[c * 66 + p2 * 2]);
    float2 ov = {xv.x + fv.x, xv.y + fv.y};
    *reinterpret_cast<float2*>(ob + (size_t)c * HW_ + p2 * 2) = ov;
  }
}

extern "C" void kernel_launch(void* const* d_in, const int* in_sizes, int n_in,
                              void* d_out, int out_size, void* d_ws, size_t ws_size,
                              hipStream_t stream) {
  const float* x      = (const float*)d_in[0];
  const float* n1w    = (const float*)d_in[1];
  const float* n1b    = (const float*)d_in[2];
  const float* qkv_w  = (const float*)d_in[3];
  const float* qkv_b  = (const float*)d_in[4];
  const float* proj_w = (const float*)d_in[5];
  const float* proj_b = (const float*)d_in[6];
  const float* rpb    = (const float*)d_in[7];
  const float* ca_w   = (const float*)d_in[8];
  const float* ca_b   = (const float*)d_in[9];
  const float* n2w    = (const float*)d_in[10];
  const float* n2b    = (const float*)d_in[11];
  const float* fc1_w  = (const float*)d_in[12];
  const float* fc1_b  = (const float*)d_in[13];
  const float* fc2_w  = (const float*)d_in[14];
  const float* fc2_b  = (const float*)d_in[15];
  float* out = (float*)d_out;

  char* ws = (char*)d_ws;
  uint16_t* y_tok   = (uint16_t*)(ws + 0);           // 50331648 B
  uint16_t* y_attn  = (uint16_t*)(ws + 50331648);    // 50331648 B
  float*    mu      = (float*)   (ws + 100663296);   // 524288 B
  float*    rsig    = (float*)   (ws + 101187584);   // 524288 B
  uint16_t* qkv_wt  = (uint16_t*)(ws + 101711872);   // 221184 B
  uint16_t* proj_wt = (uint16_t*)(ws + 101933056);   // 73728 B
  uint16_t* fc1_wt  = (uint16_t*)(ws + 102006784);   // 147456 B
  uint16_t* fc2_wt  = (uint16_t*)(ws + 102154240);   // 147456 B
  float*    rpbb    = (float*)   (ws + 102301696);   // 98304 B
  float*    part    = (float*)   (ws + 102400000);   // 1572864 B
  float*    sbuf    = (float*)   (ws + 103972864);   // 1536 B
  float*    b1f     = (float*)   (ws + 103974400);   // 1536 B (folded fc1 bias)

  hipLaunchKernelGGL(prep_kernel, dim3(1250), dim3(256), 0, stream,
                     qkv_w, proj_w, fc1_w, fc2_w, rpb, n2w, n2b, fc1_b,
                     qkv_wt, proj_wt, fc1_wt, fc2_wt, rpbb, b1f);
  hipLaunchKernelGGL(ln1_stats, dim3(512), dim3(256), 0, stream, x, mu, rsig);
  hipLaunchKernelGGL(ln1_apply_kernel, dim3(2048), dim3(256), 0, stream,
                     x, mu, rsig, n1w, n1b, y_tok);
  hipLaunchKernelGGL(attn_kernel, dim3(2048), dim3(256), 0, stream,
                     y_tok, qkv_wt, qkv_b, proj_wt, proj_b, rpbb, y_attn, part);
  hipLaunchKernelGGL(ca_s_kernel, dim3(2), dim3(768), 0, stream, part, ca_w, ca_b, sbuf);
  hipLaunchKernelGGL(fused_mlp, dim3(2048), dim3(512), 0, stream,
                     x, y_attn, sbuf, fc1_wt, b1f, fc2_wt, fc2_b, out);
}